// Round 1
// baseline (1658.249 us; speedup 1.0000x reference)
//
#include <hip/hip_runtime.h>
#include <math.h>

#define CC 256
#define HEADS 8
#define DD 32
#define GG 48
#define LL (GG*GG)      // 2304
#define NB 2
#define PTAB_N 95

// workspace layout (floats). po aliases xs (xs dead after gemm_qv/eb).
#define OFF_XS   0
#define SZ_XS    (NB*CC*LL)           // 1,179,648
#define OFF_PO   OFF_XS
#define OFF_QV   (OFF_XS + SZ_XS)
#define SZ_QV    (NB*LL*512)          // 2,359,296
#define OFF_AO   (OFF_QV + SZ_QV)
#define SZ_AO    (NB*LL*CC)
#define OFF_EB   (OFF_AO + SZ_AO)
#define SZ_EB    (NB*HEADS*LL)
#define OFF_PTX  (OFF_EB + SZ_EB)
#define SZ_PT    (PTAB_N*CC)
#define OFF_PTY  (OFF_PTX + SZ_PT)
#define OFF_WB   (OFF_PTY + SZ_PT)

// ---------------- extract strided x ----------------
__global__ void k_extract(const float* __restrict__ x, float* __restrict__ xs) {
    int idx = blockIdx.x*256 + threadIdx.x;
    if (idx >= NB*CC*LL) return;
    int s = idx % LL; int c = (idx / LL) % CC; int n = idx / (CC*LL);
    int h = s / GG, w = s % GG;
    xs[idx] = x[((n*CC + c)*96 + 2*h)*96 + 2*w];
}

// ---------------- wb[i][c] = sum_d ab[i*32+d]*Wk[(i*32+d)][c] ----------------
__global__ void k_wb(const float* __restrict__ Wk, const float* __restrict__ ab,
                     float* __restrict__ wb) {
    int i = blockIdx.x; int c = threadIdx.x;
    float acc = 0.f;
    for (int d = 0; d < DD; ++d) acc += ab[i*DD+d] * Wk[(i*DD+d)*CC + c];
    wb[i*CC + c] = acc;
}

// ---------------- ptab[dd][o] = inv_s2 * sum_e emb(2*(dd-47))[e]*Wg[o][e] ----------------
__global__ void k_ptab(const float* __restrict__ Wgx, const float* __restrict__ Wgy,
                       float* __restrict__ ptx, float* __restrict__ pty) {
    __shared__ float emb[128];
    int ddv = blockIdx.x; int which = blockIdx.y;
    int t = threadIdx.x;
    float diff = 2.0f * (float)(ddv - 47);
    if (t < 64) {
        float dim = powf(1000.0f, (float)t / 64.0f);
        float ang = diff / dim;
        emb[t]      = sinf(ang);
        emb[t + 64] = cosf(ang);
    }
    __syncthreads();
    const float* Wg = which ? Wgy : Wgx;
    float* pt = which ? pty : ptx;
    float acc = 0.f;
    #pragma unroll 8
    for (int e = 0; e < 128; ++e) acc += emb[e] * Wg[t*128 + e];
    pt[ddv*CC + t] = acc * 0.70710678118654752f;
}

// ---------------- eb[n][i][s] = sum_c wb[i][c]*xs[n][c][s] ----------------
__global__ void k_eb(const float* __restrict__ xs, const float* __restrict__ wb,
                     float* __restrict__ eb) {
    int s = blockIdx.x*256 + threadIdx.x;
    int n = blockIdx.y;
    float acc[HEADS] = {};
    const float* xp = xs + n*CC*LL + s;
    for (int c = 0; c < CC; ++c) {
        float xv = xp[c*LL];
        #pragma unroll
        for (int i = 0; i < HEADS; ++i) acc[i] += wb[i*CC+c] * xv;
    }
    #pragma unroll
    for (int i = 0; i < HEADS; ++i) eb[(n*HEADS+i)*LL + s] = acc[i];
}

// ---------------- GEMM: [Wq;Wv](512x256) @ xs(256xL) -> qv[(n*L+j)*512+o] ----------------
__global__ __launch_bounds__(256) void k_gemm_qv(const float* __restrict__ Wq,
                                                 const float* __restrict__ Wv,
                                                 const float* __restrict__ xs,
                                                 float* __restrict__ qv) {
    const int n  = blockIdx.z;
    const int m0 = blockIdx.y * 64;
    const int j0 = blockIdx.x * 64;
    __shared__ float As[16*68];
    __shared__ float Bs[16*68];
    const int t = threadIdx.x;
    const float* B = xs + n*CC*LL;
    float acc[4][4] = {};
    const int ty = t >> 4, tx = t & 15;
    for (int k0 = 0; k0 < CC; k0 += 16) {
        {
            int m = t >> 2, kq = t & 3;
            int o = m0 + m;
            const float* Arow = (o < CC) ? (Wq + o*CC) : (Wv + (o-CC)*CC);
            float4 av = *(const float4*)(Arow + k0 + kq*4);
            As[(kq*4+0)*68 + m] = av.x;
            As[(kq*4+1)*68 + m] = av.y;
            As[(kq*4+2)*68 + m] = av.z;
            As[(kq*4+3)*68 + m] = av.w;
            int kb = t >> 4, n4 = t & 15;
            float4 bv = *(const float4*)(B + (k0+kb)*LL + j0 + n4*4);
            *(float4*)(&Bs[kb*68 + n4*4]) = bv;
        }
        __syncthreads();
        #pragma unroll
        for (int k = 0; k < 16; ++k) {
            float4 a = *(const float4*)(&As[k*68 + ty*4]);
            float4 b = *(const float4*)(&Bs[k*68 + tx*4]);
            float av[4] = {a.x,a.y,a.z,a.w};
            float bv[4] = {b.x,b.y,b.z,b.w};
            #pragma unroll
            for (int p = 0; p < 4; ++p)
                #pragma unroll
                for (int q = 0; q < 4; ++q) acc[p][q] += av[p]*bv[q];
        }
        __syncthreads();
    }
    #pragma unroll
    for (int p = 0; p < 4; ++p) {
        int o = m0 + ty*4 + p;
        #pragma unroll
        for (int q = 0; q < 4; ++q) {
            int j = j0 + tx*4 + q;
            qv[(n*LL + j)*512 + o] = acc[p][q];
        }
    }
}

// ---------------- attention: 64 q-rows/block, 4-way kv split ----------------
__global__ __launch_bounds__(256) void k_attn(const float* __restrict__ qv,
                                              const float* __restrict__ eb,
                                              const float* __restrict__ ptx,
                                              const float* __restrict__ pty,
                                              float* __restrict__ ao) {
    const int t = threadIdx.x;
    const int n = blockIdx.y >> 3, i = blockIdx.y & 7;
    const int s0 = blockIdx.x * 64;
    __shared__ float qs[64*32];
    __shared__ float Eys[64*49];
    __shared__ float Exs[64*49];
    __shared__ float Bsh[LL];

    for (int idx = t; idx < 64*32; idx += 256) {
        int r = idx >> 5, d = idx & 31;
        qs[idx] = qv[(n*LL + s0 + r)*512 + i*32 + d];
    }
    for (int idx = t; idx < LL; idx += 256)
        Bsh[idx] = eb[(n*HEADS + i)*LL + idx];
    __syncthreads();

    // Ey[r][u] / Ex[r][v]
    for (int oidx = t; oidx < 64*96; oidx += 256) {
        int r = oidx / 96, j = oidx % 96;
        int s = s0 + r, h = s / GG, w = s % GG;
        int ddv; const float* tab;
        if (j < 48) { ddv = h - j + 47;      tab = pty; }
        else        { ddv = w - (j-48) + 47; tab = ptx; }
        const float4* tp = (const float4*)(tab + ddv*CC + i*32);
        const float4* qp = (const float4*)(qs + r*32);
        float acc = 0.f;
        #pragma unroll
        for (int d4 = 0; d4 < 8; ++d4) {
            float4 a = qp[d4]; float4 b = tp[d4];
            acc += a.x*b.x + a.y*b.y + a.z*b.z + a.w*b.w;
        }
        if (j < 48) Eys[r*49 + j] = acc; else Exs[r*49 + (j-48)] = acc;
    }
    __syncthreads();

    const int r = t >> 2, p = t & 3;
    const int s = s0 + r;
    float accv[32] = {};
    float S = 0.0f;
    const float* vbase = qv + (size_t)(n*LL)*512 + 256 + i*32;
    for (int jj = 0; jj < 12; ++jj) {
        int u = p + 4*jj;
        float ey = Eys[r*49 + u];
        const float* brow = Bsh + u*48;
        #pragma unroll 8
        for (int vv = 0; vv < 48; ++vv) {
            float e = brow[vv] + ey + Exs[r*49 + vv];
            float wgt = __expf(e);
            S += wgt;
            const float4* vp = (const float4*)(vbase + (size_t)(u*48+vv)*512);
            #pragma unroll
            for (int dq = 0; dq < 8; ++dq) {
                float4 v4 = vp[dq];
                accv[dq*4+0] += wgt * v4.x;
                accv[dq*4+1] += wgt * v4.y;
                accv[dq*4+2] += wgt * v4.z;
                accv[dq*4+3] += wgt * v4.w;
            }
        }
    }
    #pragma unroll
    for (int m = 1; m <= 2; m <<= 1) {
        S += __shfl_xor(S, m, 64);
        #pragma unroll
        for (int d2 = 0; d2 < 32; ++d2) accv[d2] += __shfl_xor(accv[d2], m, 64);
    }
    if (p == 0) {
        float inv = 1.0f / S;
        float* op = ao + (size_t)(n*LL + s)*CC + i*32;
        #pragma unroll
        for (int dq = 0; dq < 8; ++dq) {
            float4 o4 = make_float4(accv[dq*4]*inv, accv[dq*4+1]*inv,
                                    accv[dq*4+2]*inv, accv[dq*4+3]*inv);
            *(float4*)(op + dq*4) = o4;
        }
    }
}

// ---------------- proj GEMM: Wproj(256x256) @ ao^T -> po[n][o][s] ----------------
__global__ __launch_bounds__(256) void k_gemm_proj(const float* __restrict__ Wp,
                                                   const float* __restrict__ ao,
                                                   float* __restrict__ po) {
    const int n  = blockIdx.z;
    const int m0 = blockIdx.y * 64;
    const int j0 = blockIdx.x * 64;
    __shared__ float As[16*68];
    __shared__ float Bs[16*68];
    const int t = threadIdx.x;
    const float* Bt = ao + (size_t)n*LL*CC;   // [j][k]
    float acc[4][4] = {};
    const int ty = t >> 4, tx = t & 15;
    for (int k0 = 0; k0 < CC; k0 += 16) {
        {
            int m = t >> 2, kq = t & 3;
            float4 av = *(const float4*)(Wp + (m0+m)*CC + k0 + kq*4);
            As[(kq*4+0)*68 + m] = av.x;
            As[(kq*4+1)*68 + m] = av.y;
            As[(kq*4+2)*68 + m] = av.z;
            As[(kq*4+3)*68 + m] = av.w;
            float4 bv = *(const float4*)(Bt + (size_t)(j0+m)*CC + k0 + kq*4);
            Bs[(kq*4+0)*68 + m] = bv.x;
            Bs[(kq*4+1)*68 + m] = bv.y;
            Bs[(kq*4+2)*68 + m] = bv.z;
            Bs[(kq*4+3)*68 + m] = bv.w;
        }
        __syncthreads();
        #pragma unroll
        for (int k = 0; k < 16; ++k) {
            float4 a = *(const float4*)(&As[k*68 + ty*4]);
            float4 b = *(const float4*)(&Bs[k*68 + tx*4]);
            float av[4] = {a.x,a.y,a.z,a.w};
            float bv[4] = {b.x,b.y,b.z,b.w};
            #pragma unroll
            for (int p = 0; p < 4; ++p)
                #pragma unroll
                for (int q = 0; q < 4; ++q) acc[p][q] += av[p]*bv[q];
        }
        __syncthreads();
    }
    #pragma unroll
    for (int p = 0; p < 4; ++p) {
        int o = m0 + ty*4 + p;
        float4 ov = make_float4(acc[p][0],acc[p][1],acc[p][2],acc[p][3]);
        *(float4*)(po + (size_t)n*CC*LL + (size_t)o*LL + j0 + tx*4) = ov;
    }
}

// ---------------- bilinear x2 upsample + bias + gamma + residual ----------------
__global__ void k_final(const float* __restrict__ x, const float* __restrict__ po,
                        const float* __restrict__ bproj, const float* __restrict__ gammap,
                        float* __restrict__ out) {
    int idx = blockIdx.x*256 + threadIdx.x;
    if (idx >= NB*CC*96*96) return;
    int X = idx % 96, Y = (idx/96) % 96, o = (idx/(96*96)) % CC, n = idx/(96*96*CC);
    float gamma = gammap[0];
    float yf = Y*0.5f - 0.25f, xf = X*0.5f - 0.25f;
    float y0f = floorf(yf), x0f = floorf(xf);
    float tyy = yf - y0f, txx = xf - x0f;
    int y0 = (int)y0f, x0 = (int)x0f;
    int iy0 = max(y0,0), iy1 = min(y0+1,GG-1);
    int ix0 = max(x0,0), ix1 = min(x0+1,GG-1);
    const float* pp = po + (size_t)(n*CC + o)*LL;
    float v00 = pp[iy0*GG+ix0], v01 = pp[iy0*GG+ix1];
    float v10 = pp[iy1*GG+ix0], v11 = pp[iy1*GG+ix1];
    float vy0 = v00 + txx*(v01-v00);
    float vy1 = v10 + txx*(v11-v10);
    float bil = vy0 + tyy*(vy1-vy0);
    out[idx] = gamma*(bil + bproj[o]) + x[idx];
}

extern "C" void kernel_launch(void* const* d_in, const int* in_sizes, int n_in,
                              void* d_out, int out_size, void* d_ws, size_t ws_size,
                              hipStream_t stream) {
    const float* x   = (const float*)d_in[0];
    const float* Wq  = (const float*)d_in[1];
    const float* Wk  = (const float*)d_in[2];
    const float* Wv  = (const float*)d_in[3];
    const float* Wgx = (const float*)d_in[4];
    const float* Wgy = (const float*)d_in[5];
    const float* ab  = (const float*)d_in[6];
    const float* Wp  = (const float*)d_in[7];
    const float* bp  = (const float*)d_in[8];
    const float* gm  = (const float*)d_in[9];
    float* ws = (float*)d_ws;
    float* xs  = ws + OFF_XS;
    float* qvp = ws + OFF_QV;
    float* aop = ws + OFF_AO;
    float* ebp = ws + OFF_EB;
    float* ptxp= ws + OFF_PTX;
    float* ptyp= ws + OFF_PTY;
    float* wbp = ws + OFF_WB;
    float* pop = ws + OFF_PO;
    float* out = (float*)d_out;

    k_extract<<<(NB*CC*LL + 255)/256, 256, 0, stream>>>(x, xs);
    k_wb<<<HEADS, 256, 0, stream>>>(Wk, ab, wbp);
    k_ptab<<<dim3(PTAB_N, 2), 256, 0, stream>>>(Wgx, Wgy, ptxp, ptyp);
    k_eb<<<dim3(LL/256, NB), 256, 0, stream>>>(xs, wbp, ebp);
    k_gemm_qv<<<dim3(LL/64, 8, NB), 256, 0, stream>>>(Wq, Wv, xs, qvp);
    k_attn<<<dim3(LL/64, NB*HEADS), 256, 0, stream>>>(qvp, ebp, ptxp, ptyp, aop);
    k_gemm_proj<<<dim3(LL/64, 4, NB), 256, 0, stream>>>(Wp, aop, pop);
    k_final<<<(NB*CC*96*96 + 255)/256, 256, 0, stream>>>(x, pop, bp, gm, out);
}

// Round 2
// 337.669 us; speedup vs baseline: 4.9109x; 4.9109x over previous
//
#include <hip/hip_runtime.h>
#include <math.h>

#define CC 256
#define HEADS 8
#define DD 32
#define GG 48
#define LL (GG*GG)      // 2304
#define NB 2
#define PTAB_N 95

// workspace layout (floats). po aliases xs (xs dead after gemm_qv/eb).
#define OFF_XS   0
#define SZ_XS    (NB*CC*LL)           // 1,179,648
#define OFF_PO   OFF_XS
#define OFF_QV   (OFF_XS + SZ_XS)
#define SZ_QV    (NB*LL*512)          // 2,359,296
#define OFF_AO   (OFF_QV + SZ_QV)
#define SZ_AO    (NB*LL*CC)
#define OFF_EB   (OFF_AO + SZ_AO)
#define SZ_EB    (NB*HEADS*LL)
#define OFF_PTX  (OFF_EB + SZ_EB)
#define SZ_PT    (PTAB_N*CC)
#define OFF_PTY  (OFF_PTX + SZ_PT)
#define OFF_WB   (OFF_PTY + SZ_PT)

// ---------------- extract strided x ----------------
__global__ void k_extract(const float* __restrict__ x, float* __restrict__ xs) {
    int idx = blockIdx.x*256 + threadIdx.x;
    if (idx >= NB*CC*LL) return;
    int s = idx % LL; int c = (idx / LL) % CC; int n = idx / (CC*LL);
    int h = s / GG, w = s % GG;
    xs[idx] = x[((n*CC + c)*96 + 2*h)*96 + 2*w];
}

// ---------------- wb[i][c] = sum_d ab[i*32+d]*Wk[(i*32+d)][c] ----------------
__global__ void k_wb(const float* __restrict__ Wk, const float* __restrict__ ab,
                     float* __restrict__ wb) {
    int i = blockIdx.x; int c = threadIdx.x;
    float acc = 0.f;
    for (int d = 0; d < DD; ++d) acc += ab[i*DD+d] * Wk[(i*DD+d)*CC + c];
    wb[i*CC + c] = acc;
}

// ---------------- ptab[dd][o] = inv_s2 * sum_e emb(2*(dd-47))[e]*Wg[o][e] ----------------
__global__ void k_ptab(const float* __restrict__ Wgx, const float* __restrict__ Wgy,
                       float* __restrict__ ptx, float* __restrict__ pty) {
    __shared__ float emb[128];
    int ddv = blockIdx.x; int which = blockIdx.y;
    int t = threadIdx.x;
    float diff = 2.0f * (float)(ddv - 47);
    if (t < 64) {
        float dim = powf(1000.0f, (float)t / 64.0f);
        float ang = diff / dim;
        emb[t]      = sinf(ang);
        emb[t + 64] = cosf(ang);
    }
    __syncthreads();
    const float* Wg = which ? Wgy : Wgx;
    float* pt = which ? pty : ptx;
    float acc = 0.f;
    #pragma unroll 8
    for (int e = 0; e < 128; ++e) acc += emb[e] * Wg[t*128 + e];
    pt[ddv*CC + t] = acc * 0.70710678118654752f;
}

// ---------------- eb[n][i][s] = sum_c wb[i][c]*xs[n][c][s] ----------------
__global__ void k_eb(const float* __restrict__ xs, const float* __restrict__ wb,
                     float* __restrict__ eb) {
    int s = blockIdx.x*256 + threadIdx.x;
    int n = blockIdx.y;
    float acc[HEADS] = {};
    const float* xp = xs + n*CC*LL + s;
    for (int c = 0; c < CC; ++c) {
        float xv = xp[c*LL];
        #pragma unroll
        for (int i = 0; i < HEADS; ++i) acc[i] += wb[i*CC+c] * xv;
    }
    #pragma unroll
    for (int i = 0; i < HEADS; ++i) eb[(n*HEADS+i)*LL + s] = acc[i];
}

// ---------------- GEMM: [Wq;Wv](512x256) @ xs(256xL) -> qv[(n*L+j)*512+o] ----------------
__global__ __launch_bounds__(256) void k_gemm_qv(const float* __restrict__ Wq,
                                                 const float* __restrict__ Wv,
                                                 const float* __restrict__ xs,
                                                 float* __restrict__ qv) {
    const int n  = blockIdx.z;
    const int m0 = blockIdx.y * 64;
    const int j0 = blockIdx.x * 64;
    __shared__ float As[16*68];
    __shared__ float Bs[16*68];
    const int t = threadIdx.x;
    const float* B = xs + n*CC*LL;
    float acc[4][4] = {};
    const int ty = t >> 4, tx = t & 15;
    for (int k0 = 0; k0 < CC; k0 += 16) {
        {
            int m = t >> 2, kq = t & 3;
            int o = m0 + m;
            const float* Arow = (o < CC) ? (Wq + o*CC) : (Wv + (o-CC)*CC);
            float4 av = *(const float4*)(Arow + k0 + kq*4);
            As[(kq*4+0)*68 + m] = av.x;
            As[(kq*4+1)*68 + m] = av.y;
            As[(kq*4+2)*68 + m] = av.z;
            As[(kq*4+3)*68 + m] = av.w;
            int kb = t >> 4, n4 = t & 15;
            float4 bv = *(const float4*)(B + (k0+kb)*LL + j0 + n4*4);
            *(float4*)(&Bs[kb*68 + n4*4]) = bv;
        }
        __syncthreads();
        #pragma unroll
        for (int k = 0; k < 16; ++k) {
            float4 a = *(const float4*)(&As[k*68 + ty*4]);
            float4 b = *(const float4*)(&Bs[k*68 + tx*4]);
            float av[4] = {a.x,a.y,a.z,a.w};
            float bv[4] = {b.x,b.y,b.z,b.w};
            #pragma unroll
            for (int p = 0; p < 4; ++p)
                #pragma unroll
                for (int q = 0; q < 4; ++q) acc[p][q] += av[p]*bv[q];
        }
        __syncthreads();
    }
    #pragma unroll
    for (int p = 0; p < 4; ++p) {
        int o = m0 + ty*4 + p;
        #pragma unroll
        for (int q = 0; q < 4; ++q) {
            int j = j0 + tx*4 + q;
            qv[(n*LL + j)*512 + o] = acc[p][q];
        }
    }
}

// ---------------- attention: 64 q-rows/block, LDS-staged V tiles ----------------
// thread map: r = t>>2 (q-row 0..63), p = t&3 (kv quarter)
// kv tiled as 24 tiles x 96 rows (2 u-values x 48 vv)
__global__ __launch_bounds__(256) void k_attn(const float* __restrict__ qv,
                                              const float* __restrict__ eb,
                                              const float* __restrict__ ptx,
                                              const float* __restrict__ pty,
                                              float* __restrict__ ao) {
    const int t = threadIdx.x;
    const int n = blockIdx.y >> 3, i = blockIdx.y & 7;
    const int s0 = blockIdx.x * 64;
    __shared__ float Eys[64*49];      // stride 49: kills 8-way bank conflict
    __shared__ float Exs[64*49];
    __shared__ float ebt[96];
    __shared__ float Vt[96*36];       // stride 36: 16B-aligned, conflict-free p-spread
    float* qs = Vt;                    // overlay: q only needed in phase 1

    // stage Q tile (64 rows x 32 ch)
    #pragma unroll
    for (int l = 0; l < 2; ++l) {
        int f = t + 256*l;            // float4 index 0..511
        int r4 = f >> 3, dq = f & 7;
        float4 v4 = *(const float4*)(qv + (size_t)(n*LL + s0 + r4)*512 + i*32 + dq*4);
        *(float4*)(&qs[r4*32 + dq*4]) = v4;
    }
    __syncthreads();

    // phase 1: Ey[r][u], Ex[r][v]
    for (int oidx = t; oidx < 64*96; oidx += 256) {
        int r = oidx / 96, j = oidx % 96;
        int s = s0 + r, h = s / GG, w = s % GG;
        int ddv; const float* tab;
        if (j < 48) { ddv = h - j + 47;      tab = pty; }
        else        { ddv = w - (j-48) + 47; tab = ptx; }
        const float4* tp = (const float4*)(tab + ddv*CC + i*32);
        const float4* qp = (const float4*)(qs + r*32);
        float acc = 0.f;
        #pragma unroll
        for (int d4 = 0; d4 < 8; ++d4) {
            float4 a = qp[d4]; float4 b = tp[d4];
            acc += a.x*b.x + a.y*b.y + a.z*b.z + a.w*b.w;
        }
        if (j < 48) Eys[r*49 + j] = acc; else Exs[r*49 + (j-48)] = acc;
    }
    __syncthreads();   // Eys/Exs ready; qs still live until first Vt overwrite below

    const int r = t >> 2, p = t & 3;
    const int s = s0 + r;
    float accv[32] = {};
    float S = 0.0f;
    const float* ebg = eb + (size_t)(n*HEADS + i)*LL;
    const float* vg  = qv + (size_t)(n*LL)*512 + 256 + i*32;

    for (int tt = 0; tt < 24; ++tt) {
        __syncthreads();   // previous tile's readers done (also protects qs phase-1 reads)
        #pragma unroll
        for (int l = 0; l < 3; ++l) {
            int f = t + 256*l;        // float4 index 0..767
            int row = f >> 3, dq = f & 7;
            float4 v4 = *(const float4*)(vg + (size_t)(tt*96 + row)*512 + dq*4);
            *(float4*)(&Vt[row*36 + dq*4]) = v4;
        }
        if (t < 96) ebt[t] = ebg[tt*96 + t];
        __syncthreads();

        #pragma unroll
        for (int uu = 0; uu < 2; ++uu) {
            int u = tt*2 + uu;
            float ey = Eys[r*49 + u];
            #pragma unroll 4
            for (int m = 0; m < 12; ++m) {
                int vv = p + 4*m;
                float e = ebt[uu*48 + vv] + ey + Exs[r*49 + vv];
                float wgt = __expf(e);
                S += wgt;
                const float* vp = &Vt[(uu*48 + vv)*36];
                #pragma unroll
                for (int dq = 0; dq < 8; ++dq) {
                    float4 v4 = *(const float4*)(vp + dq*4);
                    accv[dq*4+0] += wgt * v4.x;
                    accv[dq*4+1] += wgt * v4.y;
                    accv[dq*4+2] += wgt * v4.z;
                    accv[dq*4+3] += wgt * v4.w;
                }
            }
        }
    }

    #pragma unroll
    for (int m = 1; m <= 2; m <<= 1) {
        S += __shfl_xor(S, m, 64);
        #pragma unroll
        for (int d2 = 0; d2 < 32; ++d2) accv[d2] += __shfl_xor(accv[d2], m, 64);
    }
    if (p == 0) {
        float inv = 1.0f / S;
        float* op = ao + (size_t)(n*LL + s)*CC + i*32;
        #pragma unroll
        for (int dq = 0; dq < 8; ++dq) {
            float4 o4 = make_float4(accv[dq*4]*inv, accv[dq*4+1]*inv,
                                    accv[dq*4+2]*inv, accv[dq*4+3]*inv);
            *(float4*)(op + dq*4) = o4;
        }
    }
}

// ---------------- proj GEMM: Wproj(256x256) @ ao^T -> po[n][o][s] ----------------
__global__ __launch_bounds__(256) void k_gemm_proj(const float* __restrict__ Wp,
                                                   const float* __restrict__ ao,
                                                   float* __restrict__ po) {
    const int n  = blockIdx.z;
    const int m0 = blockIdx.y * 64;
    const int j0 = blockIdx.x * 64;
    __shared__ float As[16*68];
    __shared__ float Bs[16*68];
    const int t = threadIdx.x;
    const float* Bt = ao + (size_t)n*LL*CC;   // [j][k]
    float acc[4][4] = {};
    const int ty = t >> 4, tx = t & 15;
    for (int k0 = 0; k0 < CC; k0 += 16) {
        {
            int m = t >> 2, kq = t & 3;
            float4 av = *(const float4*)(Wp + (m0+m)*CC + k0 + kq*4);
            As[(kq*4+0)*68 + m] = av.x;
            As[(kq*4+1)*68 + m] = av.y;
            As[(kq*4+2)*68 + m] = av.z;
            As[(kq*4+3)*68 + m] = av.w;
            float4 bv = *(const float4*)(Bt + (size_t)(j0+m)*CC + k0 + kq*4);
            Bs[(kq*4+0)*68 + m] = bv.x;
            Bs[(kq*4+1)*68 + m] = bv.y;
            Bs[(kq*4+2)*68 + m] = bv.z;
            Bs[(kq*4+3)*68 + m] = bv.w;
        }
        __syncthreads();
        #pragma unroll
        for (int k = 0; k < 16; ++k) {
            float4 a = *(const float4*)(&As[k*68 + ty*4]);
            float4 b = *(const float4*)(&Bs[k*68 + tx*4]);
            float av[4] = {a.x,a.y,a.z,a.w};
            float bv[4] = {b.x,b.y,b.z,b.w};
            #pragma unroll
            for (int p = 0; p < 4; ++p)
                #pragma unroll
                for (int q = 0; q < 4; ++q) acc[p][q] += av[p]*bv[q];
        }
        __syncthreads();
    }
    #pragma unroll
    for (int p = 0; p < 4; ++p) {
        int o = m0 + ty*4 + p;
        float4 ov = make_float4(acc[p][0],acc[p][1],acc[p][2],acc[p][3]);
        *(float4*)(po + (size_t)n*CC*LL + (size_t)o*LL + j0 + tx*4) = ov;
    }
}

// ---------------- bilinear x2 upsample + bias + gamma + residual ----------------
__global__ void k_final(const float* __restrict__ x, const float* __restrict__ po,
                        const float* __restrict__ bproj, const float* __restrict__ gammap,
                        float* __restrict__ out) {
    int idx = blockIdx.x*256 + threadIdx.x;
    if (idx >= NB*CC*96*96) return;
    int X = idx % 96, Y = (idx/96) % 96, o = (idx/(96*96)) % CC, n = idx/(96*96*CC);
    float gamma = gammap[0];
    float yf = Y*0.5f - 0.25f, xf = X*0.5f - 0.25f;
    float y0f = floorf(yf), x0f = floorf(xf);
    float tyy = yf - y0f, txx = xf - x0f;
    int y0 = (int)y0f, x0 = (int)x0f;
    int iy0 = max(y0,0), iy1 = min(y0+1,GG-1);
    int ix0 = max(x0,0), ix1 = min(x0+1,GG-1);
    const float* pp = po + (size_t)(n*CC + o)*LL;
    float v00 = pp[iy0*GG+ix0], v01 = pp[iy0*GG+ix1];
    float v10 = pp[iy1*GG+ix0], v11 = pp[iy1*GG+ix1];
    float vy0 = v00 + txx*(v01-v00);
    float vy1 = v10 + txx*(v11-v10);
    float bil = vy0 + tyy*(vy1-vy0);
    out[idx] = gamma*(bil + bproj[o]) + x[idx];
}

extern "C" void kernel_launch(void* const* d_in, const int* in_sizes, int n_in,
                              void* d_out, int out_size, void* d_ws, size_t ws_size,
                              hipStream_t stream) {
    const float* x   = (const float*)d_in[0];
    const float* Wq  = (const float*)d_in[1];
    const float* Wk  = (const float*)d_in[2];
    const float* Wv  = (const float*)d_in[3];
    const float* Wgx = (const float*)d_in[4];
    const float* Wgy = (const float*)d_in[5];
    const float* ab  = (const float*)d_in[6];
    const float* Wp  = (const float*)d_in[7];
    const float* bp  = (const float*)d_in[8];
    const float* gm  = (const float*)d_in[9];
    float* ws = (float*)d_ws;
    float* xs  = ws + OFF_XS;
    float* qvp = ws + OFF_QV;
    float* aop = ws + OFF_AO;
    float* ebp = ws + OFF_EB;
    float* ptxp= ws + OFF_PTX;
    float* ptyp= ws + OFF_PTY;
    float* wbp = ws + OFF_WB;
    float* pop = ws + OFF_PO;
    float* out = (float*)d_out;

    k_extract<<<(NB*CC*LL + 255)/256, 256, 0, stream>>>(x, xs);
    k_wb<<<HEADS, 256, 0, stream>>>(Wk, ab, wbp);
    k_ptab<<<dim3(PTAB_N, 2), 256, 0, stream>>>(Wgx, Wgy, ptxp, ptyp);
    k_eb<<<dim3(LL/256, NB), 256, 0, stream>>>(xs, wbp, ebp);
    k_gemm_qv<<<dim3(LL/64, 8, NB), 256, 0, stream>>>(Wq, Wv, xs, qvp);
    k_attn<<<dim3(LL/64, NB*HEADS), 256, 0, stream>>>(qvp, ebp, ptxp, ptyp, aop);
    k_gemm_proj<<<dim3(LL/64, 4, NB), 256, 0, stream>>>(Wp, aop, pop);
    k_final<<<(NB*CC*96*96 + 255)/256, 256, 0, stream>>>(x, pop, bp, gm, out);
}

// Round 4
// 211.196 us; speedup vs baseline: 7.8517x; 1.5988x over previous
//
#include <hip/hip_runtime.h>
#include <math.h>

#define CC 256
#define HEADS 8
#define DD 32
#define GG 48
#define LL (GG*GG)      // 2304
#define NB 2
#define PTAB_N 95

typedef float f32x4 __attribute__((ext_vector_type(4)));
typedef __bf16 bf16x8 __attribute__((ext_vector_type(8)));
typedef __bf16 bf16x4 __attribute__((ext_vector_type(4)));

// workspace layout (floats). po aliases xs (xs dead after gemm_qv/eb).
#define OFF_XS   0
#define SZ_XS    (NB*CC*LL)           // 1,179,648
#define OFF_PO   OFF_XS
#define OFF_QB   (OFF_XS + SZ_XS)
#define SZ_QB    (NB*LL*CC)           // 1,179,648
#define OFF_VT   (OFF_QB + SZ_QB)
#define SZ_VT_F  (NB*CC*LL/2)         // bf16 buffer, 589,824 floats
#define OFF_AO   (OFF_VT + SZ_VT_F)
#define SZ_AO    (NB*LL*CC)
#define OFF_EB   (OFF_AO + SZ_AO)
#define SZ_EB    (NB*HEADS*LL)
#define OFF_PTX  (OFF_EB + SZ_EB)
#define SZ_PT    (PTAB_N*CC)
#define OFF_PTY  (OFF_PTX + SZ_PT)
#define OFF_WB   (OFF_PTY + SZ_PT)

// ---------------- extract strided x ----------------
__global__ void k_extract(const float* __restrict__ x, float* __restrict__ xs) {
    int idx = blockIdx.x*256 + threadIdx.x;
    if (idx >= NB*CC*LL) return;
    int s = idx % LL; int c = (idx / LL) % CC; int n = idx / (CC*LL);
    int h = s / GG, w = s % GG;
    xs[idx] = x[((n*CC + c)*96 + 2*h)*96 + 2*w];
}

// ---------------- wb[i][c] = sum_d ab[i*32+d]*Wk[(i*32+d)][c] ----------------
__global__ void k_wb(const float* __restrict__ Wk, const float* __restrict__ ab,
                     float* __restrict__ wb) {
    int i = blockIdx.x; int c = threadIdx.x;
    float acc = 0.f;
    for (int d = 0; d < DD; ++d) acc += ab[i*DD+d] * Wk[(i*DD+d)*CC + c];
    wb[i*CC + c] = acc;
}

// ---------------- ptab[dd][o] = inv_s2 * sum_e emb(2*(dd-47))[e]*Wg[o][e] ----------------
__global__ void k_ptab(const float* __restrict__ Wgx, const float* __restrict__ Wgy,
                       float* __restrict__ ptx, float* __restrict__ pty) {
    __shared__ float emb[128];
    int ddv = blockIdx.x; int which = blockIdx.y;
    int t = threadIdx.x;
    float diff = 2.0f * (float)(ddv - 47);
    if (t < 64) {
        float dim = powf(1000.0f, (float)t / 64.0f);
        float ang = diff / dim;
        emb[t]      = sinf(ang);
        emb[t + 64] = cosf(ang);
    }
    __syncthreads();
    const float* Wg = which ? Wgy : Wgx;
    float* pt = which ? pty : ptx;
    float acc = 0.f;
    #pragma unroll 8
    for (int e = 0; e < 128; ++e) acc += emb[e] * Wg[t*128 + e];
    pt[ddv*CC + t] = acc * 0.70710678118654752f;
}

// ---------------- ebx[n][i][s] = exp(sum_c wb[i][c]*xs[n][c][s]) ----------------
__global__ void k_eb(const float* __restrict__ xs, const float* __restrict__ wb,
                     float* __restrict__ eb) {
    int s = blockIdx.x*256 + threadIdx.x;
    int n = blockIdx.y;
    float acc[HEADS] = {};
    const float* xp = xs + n*CC*LL + s;
    for (int c = 0; c < CC; ++c) {
        float xv = xp[c*LL];
        #pragma unroll
        for (int i = 0; i < HEADS; ++i) acc[i] += wb[i*CC+c] * xv;
    }
    #pragma unroll
    for (int i = 0; i < HEADS; ++i) eb[(n*HEADS+i)*LL + s] = __expf(acc[i]);
}

// ---------------- GEMM: [Wq;Wv](512x256) @ xs(256xL) ----------------
// Q rows (o<256)  -> qb[n][j][256] fp32
// V rows (o>=256) -> vtb[n][ch][2304] bf16 (transposed: kv contiguous)
__global__ __launch_bounds__(256) void k_gemm_qv(const float* __restrict__ Wq,
                                                 const float* __restrict__ Wv,
                                                 const float* __restrict__ xs,
                                                 float* __restrict__ qb,
                                                 __bf16* __restrict__ vtb) {
    const int n  = blockIdx.z;
    const int m0 = blockIdx.y * 64;
    const int j0 = blockIdx.x * 64;
    __shared__ float As[16*68];
    __shared__ float Bs[16*68];
    const int t = threadIdx.x;
    const float* B = xs + n*CC*LL;
    float acc[4][4] = {};
    const int ty = t >> 4, tx = t & 15;
    for (int k0 = 0; k0 < CC; k0 += 16) {
        {
            int m = t >> 2, kq = t & 3;
            int o = m0 + m;
            const float* Arow = (o < CC) ? (Wq + o*CC) : (Wv + (o-CC)*CC);
            float4 av = *(const float4*)(Arow + k0 + kq*4);
            As[(kq*4+0)*68 + m] = av.x;
            As[(kq*4+1)*68 + m] = av.y;
            As[(kq*4+2)*68 + m] = av.z;
            As[(kq*4+3)*68 + m] = av.w;
            int kb = t >> 4, n4 = t & 15;
            float4 bv = *(const float4*)(B + (k0+kb)*LL + j0 + n4*4);
            *(float4*)(&Bs[kb*68 + n4*4]) = bv;
        }
        __syncthreads();
        #pragma unroll
        for (int k = 0; k < 16; ++k) {
            float4 a = *(const float4*)(&As[k*68 + ty*4]);
            float4 b = *(const float4*)(&Bs[k*68 + tx*4]);
            float av[4] = {a.x,a.y,a.z,a.w};
            float bv[4] = {b.x,b.y,b.z,b.w};
            #pragma unroll
            for (int p = 0; p < 4; ++p)
                #pragma unroll
                for (int q = 0; q < 4; ++q) acc[p][q] += av[p]*bv[q];
        }
        __syncthreads();
    }
    if (m0 < CC) {
        #pragma unroll
        for (int p = 0; p < 4; ++p) {
            int o = m0 + ty*4 + p;
            #pragma unroll
            for (int q = 0; q < 4; ++q)
                qb[(size_t)(n*LL + j0 + tx*4 + q)*CC + o] = acc[p][q];
        }
    } else {
        #pragma unroll
        for (int p = 0; p < 4; ++p) {
            int ch = m0 - CC + ty*4 + p;   // 0..255 == i*32+d
            bf16x4 pk;
            pk[0] = (__bf16)acc[p][0];
            pk[1] = (__bf16)acc[p][1];
            pk[2] = (__bf16)acc[p][2];
            pk[3] = (__bf16)acc[p][3];
            *(bf16x4*)(vtb + (size_t)(n*CC + ch)*LL + j0 + tx*4) = pk;
        }
    }
}

// ---------------- attention: MFMA PV, factorized exp weights ----------------
// block = (n, i, 64 q-rows). 4 waves, wave mw owns q-rows s0+mw*16..+16.
// A-frag: lane holds P[rq = mw*16 + (lane&15)][k-chunk (lane>>4)*8], in-register.
// B-frag: lane reads vtb[d0 + (lane&15)][k-chunk] (bf16x8, global/L2).
__global__ __launch_bounds__(256) void k_attn(const float* __restrict__ qb,
                                              const __bf16* __restrict__ vtb,
                                              const float* __restrict__ ebx,
                                              const float* __restrict__ ptx,
                                              const float* __restrict__ pty,
                                              float* __restrict__ ao) {
    const int t = threadIdx.x;
    const int lane = t & 63;
    const int mw = t >> 6;
    const int n = blockIdx.y >> 3, i = blockIdx.y & 7;
    const int s0 = blockIdx.x * 64;

    __shared__ float Eys[64*49];   // exp(Ey), stride 49
    __shared__ float Exs[64*52];   // exp(Ex), stride 52 (16B-aligned rows)
    __shared__ float ebt[LL];      // exp(e_bias)
    float* qs = ebt;               // overlay: q tile only needed in phase 1

    // stage Q tile (64 rows x 32 ch)
    #pragma unroll
    for (int l = 0; l < 2; ++l) {
        int f = t + 256*l;
        int r4 = f >> 3, dq = f & 7;
        float4 v4 = *(const float4*)(qb + (size_t)(n*LL + s0 + r4)*CC + i*32 + dq*4);
        *(float4*)(&qs[r4*32 + dq*4]) = v4;
    }
    __syncthreads();

    // phase 1: exp(Ey[r][u]), exp(Ex[r][v])
    for (int oidx = t; oidx < 64*96; oidx += 256) {
        int r = oidx / 96, j = oidx % 96;
        int s = s0 + r, h = s / GG, w = s % GG;
        int ddv; const float* tab;
        if (j < 48) { ddv = h - j + 47;      tab = pty; }
        else        { ddv = w - (j-48) + 47; tab = ptx; }
        const float4* tp = (const float4*)(tab + ddv*CC + i*32);
        const float4* qp = (const float4*)(qs + r*32);
        float acc = 0.f;
        #pragma unroll
        for (int d4 = 0; d4 < 8; ++d4) {
            float4 a = qp[d4]; float4 b = tp[d4];
            acc += a.x*b.x + a.y*b.y + a.z*b.z + a.w*b.w;
        }
        float e = __expf(acc);
        if (j < 48) Eys[r*49 + j] = e; else Exs[r*52 + (j-48)] = e;
    }
    __syncthreads();

    // stage exp(e_bias) (overwrites qs)
    {
        const float* ebg = ebx + (size_t)(n*HEADS + i)*LL;
        for (int f = t; f < LL/4; f += 256)
            ((float4*)ebt)[f] = ((const float4*)ebg)[f];
    }
    __syncthreads();

    // main loop: zero barriers
    const int r = lane & 15;
    const int g = lane >> 4;
    const int rq = mw*16 + r;          // block-relative q-row owned by this lane
    f32x4 acc0 = {0.f,0.f,0.f,0.f}, acc1 = {0.f,0.f,0.f,0.f};
    float S = 0.f;
    const __bf16* vp0 = vtb + (size_t)(n*CC + i*32 + r)*LL;
    const __bf16* vp1 = vp0 + (size_t)16*LL;
    const float* exrow = Exs + rq*52;
    const float* eyrow = Eys + rq*49;

    for (int tt = 0; tt < 24; ++tt) {
        float ey0 = eyrow[2*tt];
        float ey1 = eyrow[2*tt+1];
        int kbase = tt*96 + g*8;
        #pragma unroll
        for (int c = 0; c < 3; ++c) {
            int kl = kbase + c*32;
            float4 e0 = *(const float4*)(ebt + kl);
            float4 e1 = *(const float4*)(ebt + kl + 4);
            int vb; float ey;
            if (c == 0)      { vb = g*8;      ey = ey0; }
            else if (c == 2) { vb = 16 + g*8; ey = ey1; }
            else { vb = (g < 2) ? (32 + g*8) : ((g-2)*8);
                   ey = (g < 2) ? ey0 : ey1; }
            float4 x0 = *(const float4*)(exrow + vb);
            float4 x1 = *(const float4*)(exrow + vb + 4);
            float w0 = e0.x*x0.x*ey, w1 = e0.y*x0.y*ey;
            float w2 = e0.z*x0.z*ey, w3 = e0.w*x0.w*ey;
            float w4 = e1.x*x1.x*ey, w5 = e1.y*x1.y*ey;
            float w6 = e1.z*x1.z*ey, w7 = e1.w*x1.w*ey;
            S += ((w0+w1)+(w2+w3)) + ((w4+w5)+(w6+w7));
            bf16x8 av;
            av[0]=(__bf16)w0; av[1]=(__bf16)w1; av[2]=(__bf16)w2; av[3]=(__bf16)w3;
            av[4]=(__bf16)w4; av[5]=(__bf16)w5; av[6]=(__bf16)w6; av[7]=(__bf16)w7;
            bf16x8 b0 = *(const bf16x8*)(vp0 + kl);
            bf16x8 b1 = *(const bf16x8*)(vp1 + kl);
            acc0 = __builtin_amdgcn_mfma_f32_16x16x32_bf16(av, b0, acc0, 0, 0, 0);
            acc1 = __builtin_amdgcn_mfma_f32_16x16x32_bf16(av, b1, acc1, 0, 0, 0);
        }
    }

    // S: reduce over k-chunk groups (lanes 16 apart)
    S += __shfl_xor(S, 16, 64);
    S += __shfl_xor(S, 32, 64);

    // D layout: row = g*4 + reg, col = lane&15 (+16 for acc1)
    #pragma unroll
    for (int reg = 0; reg < 4; ++reg) {
        int row = g*4 + reg;
        float inv = 1.0f / __shfl(S, row, 64);
        size_t base = (size_t)(n*LL + s0 + mw*16 + row)*CC + i*32;
        ao[base + r]      = acc0[reg] * inv;
        ao[base + 16 + r] = acc1[reg] * inv;
    }
}

// ---------------- proj GEMM: Wproj(256x256) @ ao^T -> po[n][o][s] ----------------
__global__ __launch_bounds__(256) void k_gemm_proj(const float* __restrict__ Wp,
                                                   const float* __restrict__ ao,
                                                   float* __restrict__ po) {
    const int n  = blockIdx.z;
    const int m0 = blockIdx.y * 64;
    const int j0 = blockIdx.x * 64;
    __shared__ float As[16*68];
    __shared__ float Bs[16*68];
    const int t = threadIdx.x;
    const float* Bt = ao + (size_t)n*LL*CC;   // [j][k]
    float acc[4][4] = {};
    const int ty = t >> 4, tx = t & 15;
    for (int k0 = 0; k0 < CC; k0 += 16) {
        {
            int m = t >> 2, kq = t & 3;
            float4 av = *(const float4*)(Wp + (m0+m)*CC + k0 + kq*4);
            As[(kq*4+0)*68 + m] = av.x;
            As[(kq*4+1)*68 + m] = av.y;
            As[(kq*4+2)*68 + m] = av.z;
            As[(kq*4+3)*68 + m] = av.w;
            float4 bv = *(const float4*)(Bt + (size_t)(j0+m)*CC + k0 + kq*4);
            Bs[(kq*4+0)*68 + m] = bv.x;
            Bs[(kq*4+1)*68 + m] = bv.y;
            Bs[(kq*4+2)*68 + m] = bv.z;
            Bs[(kq*4+3)*68 + m] = bv.w;
        }
        __syncthreads();
        #pragma unroll
        for (int k = 0; k < 16; ++k) {
            float4 a = *(const float4*)(&As[k*68 + ty*4]);
            float4 b = *(const float4*)(&Bs[k*68 + tx*4]);
            float av[4] = {a.x,a.y,a.z,a.w};
            float bv[4] = {b.x,b.y,b.z,b.w};
            #pragma unroll
            for (int p = 0; p < 4; ++p)
                #pragma unroll
                for (int q = 0; q < 4; ++q) acc[p][q] += av[p]*bv[q];
        }
        __syncthreads();
    }
    #pragma unroll
    for (int p = 0; p < 4; ++p) {
        int o = m0 + ty*4 + p;
        float4 ov = make_float4(acc[p][0],acc[p][1],acc[p][2],acc[p][3]);
        *(float4*)(po + (size_t)n*CC*LL + (size_t)o*LL + j0 + tx*4) = ov;
    }
}

// ---------------- bilinear x2 upsample + bias + gamma + residual ----------------
__global__ void k_final(const float* __restrict__ x, const float* __restrict__ po,
                        const float* __restrict__ bproj, const float* __restrict__ gammap,
                        float* __restrict__ out) {
    int idx = blockIdx.x*256 + threadIdx.x;
    if (idx >= NB*CC*96*96) return;
    int X = idx % 96, Y = (idx/96) % 96, o = (idx/(96*96)) % CC, n = idx/(96*96*CC);
    float gamma = gammap[0];
    float yf = Y*0.5f - 0.25f, xf = X*0.5f - 0.25f;
    float y0f = floorf(yf), x0f = floorf(xf);
    float tyy = yf - y0f, txx = xf - x0f;
    int y0 = (int)y0f, x0 = (int)x0f;
    int iy0 = max(y0,0), iy1 = min(y0+1,GG-1);
    int ix0 = max(x0,0), ix1 = min(x0+1,GG-1);
    const float* pp = po + (size_t)(n*CC + o)*LL;
    float v00 = pp[iy0*GG+ix0], v01 = pp[iy0*GG+ix1];
    float v10 = pp[iy1*GG+ix0], v11 = pp[iy1*GG+ix1];
    float vy0 = v00 + txx*(v01-v00);
    float vy1 = v10 + txx*(v11-v10);
    float bil = vy0 + tyy*(vy1-vy0);
    out[idx] = gamma*(bil + bproj[o]) + x[idx];
}

extern "C" void kernel_launch(void* const* d_in, const int* in_sizes, int n_in,
                              void* d_out, int out_size, void* d_ws, size_t ws_size,
                              hipStream_t stream) {
    const float* x   = (const float*)d_in[0];
    const float* Wq  = (const float*)d_in[1];
    const float* Wk  = (const float*)d_in[2];
    const float* Wv  = (const float*)d_in[3];
    const float* Wgx = (const float*)d_in[4];
    const float* Wgy = (const float*)d_in[5];
    const float* ab  = (const float*)d_in[6];
    const float* Wp  = (const float*)d_in[7];
    const float* bp  = (const float*)d_in[8];
    const float* gm  = (const float*)d_in[9];
    float* ws = (float*)d_ws;
    float* xs  = ws + OFF_XS;
    float* qbp = ws + OFF_QB;
    __bf16* vtb = (__bf16*)(ws + OFF_VT);
    float* aop = ws + OFF_AO;
    float* ebp = ws + OFF_EB;
    float* ptxp= ws + OFF_PTX;
    float* ptyp= ws + OFF_PTY;
    float* wbp = ws + OFF_WB;
    float* pop = ws + OFF_PO;
    float* out = (float*)d_out;

    k_extract<<<(NB*CC*LL + 255)/256, 256, 0, stream>>>(x, xs);
    k_wb<<<HEADS, 256, 0, stream>>>(Wk, ab, wbp);
    k_ptab<<<dim3(PTAB_N, 2), 256, 0, stream>>>(Wgx, Wgy, ptxp, ptyp);
    k_eb<<<dim3(LL/256, NB), 256, 0, stream>>>(xs, wbp, ebp);
    k_gemm_qv<<<dim3(LL/64, 8, NB), 256, 0, stream>>>(Wq, Wv, xs, qbp, vtb);
    k_attn<<<dim3(LL/64, NB*HEADS), 256, 0, stream>>>(qbp, vtb, ebp, ptxp, ptyp, aop);
    k_gemm_proj<<<dim3(LL/64, 4, NB), 256, 0, stream>>>(Wp, aop, pop);
    k_final<<<(NB*CC*96*96 + 255)/256, 256, 0, stream>>>(x, pop, bp, gm, out);
}